// Round 16
// baseline (250.811 us; speedup 1.0000x reference)
//
#include <hip/hip_runtime.h>
#include <math.h>

#define R2 2500.0f
#define EPSF 1e-8f

constexpr int H   = 256;   // feature dim (fixed by problem)
constexpr int HH  = 128;   // hidden dim
constexpr int NB  = 8;     // col-buckets per row (bucket = col>>11 -> 2MB of x)
constexpr int BSH = 11;    // bucket shift
constexpr int RPW = 4;     // rows per wave in k_fvar (R9-proven best)

// ---------------- K1f: degree count + cell count (fused, vectorized) -------
__global__ void __launch_bounds__(256) k_degcell(
    const int* __restrict__ row, const int* __restrict__ col,
    int* __restrict__ deg4, const float* __restrict__ coords,
    int* __restrict__ cellcnt, int EB4, int N) {
    if ((int)blockIdx.x < EB4) {
        int e4 = blockIdx.x * 256 + threadIdx.x;
        int4 r = ((const int4*)row)[e4];
        int4 c = ((const int4*)col)[e4];
        atomicAdd(&deg4[r.x * NB + (c.x >> BSH)], 1);
        atomicAdd(&deg4[r.y * NB + (c.y >> BSH)], 1);
        atomicAdd(&deg4[r.z * NB + (c.z >> BSH)], 1);
        atomicAdd(&deg4[r.w * NB + (c.w >> BSH)], 1);
    } else {
        int t2 = ((int)blockIdx.x - EB4) * 256 + threadIdx.x;   // 2 points
        float4 cc = ((const float4*)coords)[t2];
        int cx0 = (int)(cc.x * 0.02f); if (cx0 > 19) cx0 = 19;
        int cy0 = (int)(cc.y * 0.02f); if (cy0 > 19) cy0 = 19;
        int cx1 = (int)(cc.z * 0.02f); if (cx1 > 19) cx1 = 19;
        int cy1 = (int)(cc.w * 0.02f); if (cy1 > 19) cy1 = 19;
        atomicAdd(&cellcnt[cy0 * 20 + cx0], 1);
        atomicAdd(&cellcnt[cy1 * 20 + cx1], 1);
    }
}

// ---------------- K2: scat (self-computed chunk sums) + cellscan -----------
// k_bsum folded in: each scat block streams deg4 (512KB, L2/L3-hot,
// coalesced) computing all 128 chunk sums itself, then scans in LDS.
// Integer adds -> exact same rp4 as the two-kernel version. -1 dispatch.
__global__ void __launch_bounds__(512) k_scatcell(
    const int* __restrict__ deg4,
    int* __restrict__ rp4, int* __restrict__ cur4, int M,
    const int* __restrict__ cellcnt, int* __restrict__ cellstart,
    int* __restrict__ cellcur) {
    __shared__ int s[512];
    int t = threadIdx.x;
    int blk = blockIdx.x;
    if (blk < gridDim.x - 1) {
        // chunk sums: 8 waves x 16 chunks each; chunk = 1024 ints = 256 int4
        int wv8 = t >> 6, ln = t & 63;
        for (int c = wv8; c < 128; c += 8) {
            int sum = 0;
#pragma unroll
            for (int k = 0; k < 4; k++) {
                int4 v = ((const int4*)deg4)[c * 256 + k * 64 + ln];
                sum += v.x + v.y + v.z + v.w;
            }
#pragma unroll
            for (int off = 32; off > 0; off >>= 1) sum += __shfl_xor(sum, off, 64);
            if (ln == 0) s[c] = sum;
        }
        __syncthreads();
        // inclusive scan of s[0..127]
        for (int off = 1; off < 128; off <<= 1) {
            int v = 0, add = 0;
            if (t < 128) { v = s[t]; add = (t >= off) ? s[t - off] : 0; }
            __syncthreads();
            if (t < 128) s[t] = v + add;
            __syncthreads();
        }
        int boff = (blk > 0) ? s[blk - 1] : 0;
        if (t < 256) {
            int lane = t & 63, w = t >> 6;
            int4 v = ((const int4*)deg4)[blk * 256 + t];
            int tsum = v.x + v.y + v.z + v.w;
            int incl = tsum;
#pragma unroll
            for (int off = 1; off < 64; off <<= 1) {
                int n = __shfl_up(incl, off, 64);
                if (lane >= off) incl += n;
            }
            __shared__ int wsum[4];
            if (lane == 63) wsum[w] = incl;
            __syncthreads();
            int woff = 0;
#pragma unroll
            for (int k = 0; k < 4; k++) woff += (k < w) ? wsum[k] : 0;
            int excl = boff + woff + (incl - tsum);
            int4 r;
            r.x = excl;
            r.y = excl + v.x;
            r.z = excl + v.x + v.y;
            r.w = excl + v.x + v.y + v.z;
            ((int4*)rp4)[blk * 256 + t]  = r;
            ((int4*)cur4)[blk * 256 + t] = r;
            if (blk == 127 && t == 255) rp4[M] = excl + tsum;
        }
    } else {
        s[t] = (t < 400) ? cellcnt[t] : 0;
        __syncthreads();
        for (int off = 1; off < 512; off <<= 1) {
            int v = s[t];
            int add = (t >= off) ? s[t - off] : 0;
            __syncthreads();
            s[t] = v + add;
            __syncthreads();
        }
        if (t < 400) {
            int excl = (t > 0) ? s[t - 1] : 0;
            cellstart[t] = excl;
            cellcur[t]   = excl;
        }
        if (t == 400) cellstart[400] = s[399];
    }
}

// ---------------- K3f: CSR fill + cell fill (fused, vectorized) ------------
__global__ void __launch_bounds__(256) k_fillcell(
    const int* __restrict__ row, const int* __restrict__ col,
    int* __restrict__ cur4, int* __restrict__ cols,
    const float* __restrict__ coords, int* __restrict__ cellcur,
    float4* __restrict__ pts, int EB4, int N) {
    if ((int)blockIdx.x < EB4) {
        int e4 = blockIdx.x * 256 + threadIdx.x;
        int4 r = ((const int4*)row)[e4];
        int4 c = ((const int4*)col)[e4];
        int p0 = atomicAdd(&cur4[r.x * NB + (c.x >> BSH)], 1); cols[p0] = c.x;
        int p1 = atomicAdd(&cur4[r.y * NB + (c.y >> BSH)], 1); cols[p1] = c.y;
        int p2 = atomicAdd(&cur4[r.z * NB + (c.z >> BSH)], 1); cols[p2] = c.z;
        int p3 = atomicAdd(&cur4[r.w * NB + (c.w >> BSH)], 1); cols[p3] = c.w;
    } else {
        int t2 = ((int)blockIdx.x - EB4) * 256 + threadIdx.x;
        float4 cc = ((const float4*)coords)[t2];
        int i0 = t2 * 2;
        int cx0 = (int)(cc.x * 0.02f); if (cx0 > 19) cx0 = 19;
        int cy0 = (int)(cc.y * 0.02f); if (cy0 > 19) cy0 = 19;
        int p0 = atomicAdd(&cellcur[cy0 * 20 + cx0], 1);
        pts[p0] = make_float4(cc.x, cc.y, cc.x * cc.x + cc.y * cc.y,
                              __int_as_float(i0));
        int cx1 = (int)(cc.z * 0.02f); if (cx1 > 19) cx1 = 19;
        int cy1 = (int)(cc.w * 0.02f); if (cy1 > 19) cy1 = 19;
        int p1 = atomicAdd(&cellcur[cy1 * 20 + cx1], 1);
        pts[p1] = make_float4(cc.z, cc.w, cc.z * cc.z + cc.w * cc.w,
                              __int_as_float(i0 + 1));
    }
}

// ---------------- K5: fvar + dgrid fused (256,4), DUMMY-MASKED gather ------
// vs R15: invalid batch slots load a LANE-INVARIANT 16B at xb[0] (one
// broadcast line) instead of a clamped-dup full row (16 lines). With avg
// segment m=4, dups were ~half the L1-return/MSHR occupancy. Exact *1/*0
// FMA masking unchanged -> bit-identical. This is R10's trick, now isolated
// at RPW=4 (R10 confounded it with the RPW=2 FETCH regression).
__global__ void __launch_bounds__(256, 4) k_fvar_dgrid(
    const float* __restrict__ x, const int* __restrict__ rp4,
    const int* __restrict__ cols, float* __restrict__ fvar,
    const float4* __restrict__ pts, const int* __restrict__ cellstart,
    int* __restrict__ dens, int FBk, int N) {
    int wave = threadIdx.x >> 6;
    int lane = threadIdx.x & 63;
    if ((int)blockIdx.x < FBk) {
        int i0 = (blockIdx.x * 4 + wave) * RPW;
        const float4* xb = (const float4*)x;   // 64 float4 per row
        int bnd = rp4[i0 * NB + (lane < 32 ? lane : 32)];

        float4 acc0 = make_float4(0.f, 0.f, 0.f, 0.f);
        float4 acc1 = make_float4(0.f, 0.f, 0.f, 0.f);
        float4 acc2 = make_float4(0.f, 0.f, 0.f, 0.f);
        float4 acc3 = make_float4(0.f, 0.f, 0.f, 0.f);

        for (int b = 0; b < NB; b++) {
#pragma unroll
            for (int r = 0; r < RPW; r++) {
                float4& a = (r == 0) ? acc0 : (r == 1) ? acc1
                          : (r == 2) ? acc2 : acc3;
                int s = __shfl(bnd, r * NB + b, 64);
                int e = __shfl(bnd, r * NB + b + 1, 64);
                for (int p0 = s; p0 < e; p0 += 64) {
                    int m = e - p0; if (m > 64) m = 64;
                    int idx = cols[p0 + (lane < m ? lane : m - 1)];
                    for (int j = 0; j < m; j += 8) {
                        int nb2 = m - j; if (nb2 > 8) nb2 = 8;
                        size_t o0 = (size_t)__shfl(idx, j + 0, 64) * 64 + lane;
                        size_t o1 = (1 < nb2) ? (size_t)__shfl(idx, j + 1, 64) * 64 + lane : 0;
                        size_t o2 = (2 < nb2) ? (size_t)__shfl(idx, j + 2, 64) * 64 + lane : 0;
                        size_t o3 = (3 < nb2) ? (size_t)__shfl(idx, j + 3, 64) * 64 + lane : 0;
                        size_t o4 = (4 < nb2) ? (size_t)__shfl(idx, j + 4, 64) * 64 + lane : 0;
                        size_t o5 = (5 < nb2) ? (size_t)__shfl(idx, j + 5, 64) * 64 + lane : 0;
                        size_t o6 = (6 < nb2) ? (size_t)__shfl(idx, j + 6, 64) * 64 + lane : 0;
                        size_t o7 = (7 < nb2) ? (size_t)__shfl(idx, j + 7, 64) * 64 + lane : 0;
                        float4 g0 = xb[o0];
                        float4 g1 = xb[o1];
                        float4 g2 = xb[o2];
                        float4 g3 = xb[o3];
                        float4 g4 = xb[o4];
                        float4 g5 = xb[o5];
                        float4 g6 = xb[o6];
                        float4 g7 = xb[o7];
                        float w1 = (1 < nb2) ? 1.0f : 0.0f;
                        float w2 = (2 < nb2) ? 1.0f : 0.0f;
                        float w3 = (3 < nb2) ? 1.0f : 0.0f;
                        float w4 = (4 < nb2) ? 1.0f : 0.0f;
                        float w5 = (5 < nb2) ? 1.0f : 0.0f;
                        float w6 = (6 < nb2) ? 1.0f : 0.0f;
                        float w7 = (7 < nb2) ? 1.0f : 0.0f;
                        a.x += g0.x; a.y += g0.y; a.z += g0.z; a.w += g0.w;
                        a.x = fmaf(g1.x, w1, a.x); a.y = fmaf(g1.y, w1, a.y);
                        a.z = fmaf(g1.z, w1, a.z); a.w = fmaf(g1.w, w1, a.w);
                        a.x = fmaf(g2.x, w2, a.x); a.y = fmaf(g2.y, w2, a.y);
                        a.z = fmaf(g2.z, w2, a.z); a.w = fmaf(g2.w, w2, a.w);
                        a.x = fmaf(g3.x, w3, a.x); a.y = fmaf(g3.y, w3, a.y);
                        a.z = fmaf(g3.z, w3, a.z); a.w = fmaf(g3.w, w3, a.w);
                        a.x = fmaf(g4.x, w4, a.x); a.y = fmaf(g4.y, w4, a.y);
                        a.z = fmaf(g4.z, w4, a.z); a.w = fmaf(g4.w, w4, a.w);
                        a.x = fmaf(g5.x, w5, a.x); a.y = fmaf(g5.y, w5, a.y);
                        a.z = fmaf(g5.z, w5, a.z); a.w = fmaf(g5.w, w5, a.w);
                        a.x = fmaf(g6.x, w6, a.x); a.y = fmaf(g6.y, w6, a.y);
                        a.z = fmaf(g6.z, w6, a.z); a.w = fmaf(g6.w, w6, a.w);
                        a.x = fmaf(g7.x, w7, a.x); a.y = fmaf(g7.y, w7, a.y);
                        a.z = fmaf(g7.z, w7, a.z); a.w = fmaf(g7.w, w7, a.w);
                    }
                }
            }
        }

#define FIN(RR, ACCR)                                                   \
        {                                                               \
            int i = i0 + (RR);                                          \
            float cnt = fmaxf((float)(__shfl(bnd, (RR) * NB + NB, 64) - \
                                      __shfl(bnd, (RR) * NB, 64)), 1.0f); \
            float4 xi = xb[(size_t)i * 64 + lane];                      \
            float dx = xi.x - ACCR.x / cnt;                             \
            float dy = xi.y - ACCR.y / cnt;                             \
            float dz = xi.z - ACCR.z / cnt;                             \
            float dw = xi.w - ACCR.w / cnt;                             \
            float ss = dx * dx + dy * dy + dz * dz + dw * dw;           \
            _Pragma("unroll")                                           \
            for (int off = 32; off > 0; off >>= 1) ss += __shfl_xor(ss, off, 64); \
            if (lane == 0) fvar[i] = sqrtf(ss);                         \
        }

        FIN(0, acc0);
        FIN(1, acc1);
        FIN(2, acc2);
        FIN(3, acc3);
#undef FIN
    } else {
        // dgrid: one wave per point (R6-proven body)
        int t = ((int)blockIdx.x - FBk) * 4 + wave;
        float4 p = pts[t];
        int cx = (int)(p.x * 0.02f); if (cx > 19) cx = 19;
        int cy = (int)(p.y * 0.02f); if (cy > 19) cy = 19;
        int x0 = cx - 2; if (x0 < 0) x0 = 0;
        int x1 = cx + 2; if (x1 > 19) x1 = 19;
        int y0 = cy - 2; if (y0 < 0) y0 = 0;
        int y1 = cy + 2; if (y1 > 19) y1 = 19;
        int cnt = 0;
        for (int yy = y0; yy <= y1; yy++) {
            int rowb = yy * 20;
            int s = cellstart[rowb + x0];
            int e = cellstart[rowb + x1 + 1];
            for (int q = s + lane; q < e; q += 64) {
                float4 pq = pts[q];
                float dot = p.x * pq.x + p.y * pq.y;
                float d2 = (p.z + pq.z) - 2.0f * dot;
                cnt += (d2 <= R2) ? 1 : 0;
            }
        }
#pragma unroll
        for (int off = 32; off > 0; off >>= 1) cnt += __shfl_xor(cnt, off, 64);
        if (lane == 0) dens[__float_as_int(p.w)] = cnt;
    }
}

// ---------------- K5b: maxima reduction (R13-proven, ~3us) ----------------
__global__ void __launch_bounds__(256) k_scal(
    const int* __restrict__ rp4, const int* __restrict__ dens,
    const float* __restrict__ fvar, int* __restrict__ scal, int N) {
    __shared__ int sd[4], sn[4];
    __shared__ float sf[4];
    int t = threadIdx.x;
    int g = blockIdx.x * 256 + t;
    int stride = 256 * gridDim.x;
    int md = 0, mn = 0;
    float mf = 0.f;
    for (int i = g; i < N; i += stride) {
        md = max(md, rp4[(i + 1) * NB] - rp4[i * NB]);
        mn = max(mn, dens[i]);
        mf = fmaxf(mf, fvar[i]);
    }
#pragma unroll
    for (int off = 32; off > 0; off >>= 1) {
        md = max(md, __shfl_xor(md, off, 64));
        mn = max(mn, __shfl_xor(mn, off, 64));
        mf = fmaxf(mf, __shfl_xor(mf, off, 64));
    }
    int w = t >> 6, l = t & 63;
    if (l == 0) { sd[w] = md; sn[w] = mn; sf[w] = mf; }
    __syncthreads();
    if (t == 0) {
#pragma unroll
        for (int k = 1; k < 4; k++) {
            md = max(md, sd[k]);
            mn = max(mn, sn[k]);
            mf = fmaxf(mf, sf[k]);
        }
        atomicMax(&scal[0], md);
        atomicMax(&scal[1], mn);
        atomicMax(&scal[2], __float_as_int(mf));   // nonneg float: int-max ok
    }
}

// ---------------- K6: tiny MLP (R13-proven) ----------------
__global__ void __launch_bounds__(256) k_mlp(
    const float* __restrict__ w1, const float* __restrict__ b1,
    const float* __restrict__ w2, const float* __restrict__ b2,
    const int* __restrict__ rp4, const int* __restrict__ dens,
    const float* __restrict__ fvar, const int* __restrict__ scal,
    float* __restrict__ out, int N) {
    __shared__ float sh_h[HH];
    int j = threadIdx.x;
    float wv[HH];
#pragma unroll
    for (int l = 0; l < HH; l++) wv[l] = w2[l * H + j];
    float bj = b2[j];
    float maxdeg  = (float)scal[0] + EPSF;
    float maxdens = (float)(scal[1] - 1) + EPSF;
    float maxfv   = __int_as_float(scal[2]) + EPSF;
    float w1a = 0.f, w1b = 0.f, w1c = 0.f, b1j = 0.f;
    if (j < HH) { w1a = w1[j]; w1b = w1[HH + j]; w1c = w1[2 * HH + j]; b1j = b1[j]; }
    for (int i = blockIdx.x; i < N; i += gridDim.x) {
        float f0 = (float)(rp4[(i + 1) * NB] - rp4[i * NB]) / maxdeg;
        float f1 = (float)(dens[i] - 1) / maxdens;
        float f2 = fvar[i] / maxfv;
        if (j < HH) {
            float h = f0 * w1a + f1 * w1b + f2 * w1c + b1j;
            sh_h[j] = fmaxf(h, 0.0f);
        }
        __syncthreads();
        float acc = bj;
#pragma unroll
        for (int l = 0; l < HH; l++) acc = fmaf(sh_h[l], wv[l], acc);
        out[(size_t)i * H + j] = acc;
        __syncthreads();
    }
}

extern "C" void kernel_launch(void* const* d_in, const int* in_sizes, int n_in,
                              void* d_out, int out_size, void* d_ws, size_t ws_size,
                              hipStream_t stream) {
    const float* x      = (const float*)d_in[0];
    const int*   ei     = (const int*)d_in[1];
    const float* coords = (const float*)d_in[2];
    const float* w1     = (const float*)d_in[3];
    const float* b1     = (const float*)d_in[4];
    const float* w2     = (const float*)d_in[5];
    const float* b2     = (const float*)d_in[6];
    float* out = (float*)d_out;

    const int N = in_sizes[2] / 2;   // 16384
    const int E = in_sizes[1] / 2;   // 524288
    const int M = N * NB;            // 131072
    const int NBLK = M / 1024;       // 128 scan blocks
    const int EB4 = E / 1024;        // 512 edge blocks (4 edges/thread)
    const int CB2 = N / 512;         // 32 coord blocks (2 points/thread)
    const int FBk = N / (4 * RPW);   // 1024 fvar blocks
    const int DB  = N / 4;           // 4096 dgrid blocks
    const int* row = ei;
    const int* col = ei + E;

    // workspace layout (int32 elements; int4/float4 arrays 16B-aligned)
    int* ws        = (int*)d_ws;
    int* scal      = ws;                       // [4]     zeroed
    int* deg4      = ws + 4;                   // [M]     zeroed  (16B-aligned)
    int* cellcnt   = ws + 4 + M;               // [404]   zeroed  (400 used)
    int* rp4       = ws + 408 + M;             // [M+4]           (16B-aligned)
    int* cur4      = rp4 + M + 4;              // [M]             (16B-aligned)
    int* cellstart = cur4 + M;                 // [404]   (401 used)
    int* cellcur   = cellstart + 404;          // [400]
    int* dens_cnt  = cellcur + 400;            // [N]
    float* fvarp   = (float*)(dens_cnt + N);   // [N]
    int* bsum      = dens_cnt + 2 * N;         // [128]  (unused pad)
    int* boff      = bsum + 128;               // [128]  (layout pad)
    int* cols      = boff + 128;               // [E]
    float4* pts    = (float4*)(cols + E);      // [N]  (16B-aligned)
    (void)bsum;

    hipMemsetAsync(ws, 0, (size_t)(408 + M) * sizeof(int), stream);

    k_degcell<<<EB4 + CB2, 256, 0, stream>>>(row, col, deg4, coords, cellcnt,
                                             EB4, N);
    k_scatcell<<<NBLK + 1, 512, 0, stream>>>(deg4, rp4, cur4, M,
                                             cellcnt, cellstart, cellcur);
    k_fillcell<<<EB4 + CB2, 256, 0, stream>>>(row, col, cur4, cols,
                                              coords, cellcur, pts, EB4, N);

    k_fvar_dgrid<<<FBk + DB, 256, 0, stream>>>(x, rp4, cols, fvarp,
                                               pts, cellstart, dens_cnt, FBk, N);

    k_scal<<<64, 256, 0, stream>>>(rp4, dens_cnt, fvarp, scal, N);

    k_mlp<<<1024, 256, 0, stream>>>(w1, b1, w2, b2, rp4, dens_cnt, fvarp, scal,
                                    out, N);
}

// Round 18
// 241.296 us; speedup vs baseline: 1.0394x; 1.0394x over previous
//
#include <hip/hip_runtime.h>
#include <math.h>

#define R2 2500.0f
#define EPSF 1e-8f

constexpr int H   = 256;   // feature dim (fixed by problem)
constexpr int HH  = 128;   // hidden dim
constexpr int NB  = 8;     // col-buckets per row (bucket = col>>11 -> 2MB of x)
constexpr int BSH = 11;    // bucket shift
constexpr int RPW = 4;     // rows per wave in k_fvar (R9-proven best)

// ---------------- K1f: degree count + cell count (fused, vectorized) -------
__global__ void __launch_bounds__(256) k_degcell(
    const int* __restrict__ row, const int* __restrict__ col,
    int* __restrict__ deg4, const float* __restrict__ coords,
    int* __restrict__ cellcnt, int EB4, int N) {
    if ((int)blockIdx.x < EB4) {
        int e4 = blockIdx.x * 256 + threadIdx.x;
        int4 r = ((const int4*)row)[e4];
        int4 c = ((const int4*)col)[e4];
        atomicAdd(&deg4[r.x * NB + (c.x >> BSH)], 1);
        atomicAdd(&deg4[r.y * NB + (c.y >> BSH)], 1);
        atomicAdd(&deg4[r.z * NB + (c.z >> BSH)], 1);
        atomicAdd(&deg4[r.w * NB + (c.w >> BSH)], 1);
    } else {
        int t2 = ((int)blockIdx.x - EB4) * 256 + threadIdx.x;   // 2 points
        float4 cc = ((const float4*)coords)[t2];
        int cx0 = (int)(cc.x * 0.02f); if (cx0 > 19) cx0 = 19;
        int cy0 = (int)(cc.y * 0.02f); if (cy0 > 19) cy0 = 19;
        int cx1 = (int)(cc.z * 0.02f); if (cx1 > 19) cx1 = 19;
        int cy1 = (int)(cc.w * 0.02f); if (cy1 > 19) cy1 = 19;
        atomicAdd(&cellcnt[cy0 * 20 + cx0], 1);
        atomicAdd(&cellcnt[cy1 * 20 + cx1], 1);
    }
}

// ---------------- K2a: per-block sums over M (128 blocks) ----------------
__global__ void __launch_bounds__(256) k_bsum(const int* __restrict__ deg4,
                                              int* __restrict__ bsum) {
    int t = threadIdx.x;
    int4 v = ((const int4*)deg4)[blockIdx.x * 256 + t];
    int sum = v.x + v.y + v.z + v.w;
#pragma unroll
    for (int off = 32; off > 0; off >>= 1) sum += __shfl_xor(sum, off, 64);
    __shared__ int sw[4];
    if ((t & 63) == 0) sw[t >> 6] = sum;
    __syncthreads();
    if (t == 0) bsum[blockIdx.x] = sw[0] + sw[1] + sw[2] + sw[3];
}

// ---------------- K2f: scat (with internal bsum prefix) + cellscan --------
__global__ void __launch_bounds__(512) k_scatcell(
    const int* __restrict__ deg4, const int* __restrict__ bsum,
    int* __restrict__ rp4, int* __restrict__ cur4, int M,
    const int* __restrict__ cellcnt, int* __restrict__ cellstart,
    int* __restrict__ cellcur) {
    __shared__ int s[512];
    int t = threadIdx.x;
    int blk = blockIdx.x;
    if (blk < gridDim.x - 1) {
        s[t] = (t < 128) ? bsum[t] : 0;
        __syncthreads();
        for (int off = 1; off < 128; off <<= 1) {
            int v = 0, add = 0;
            if (t < 128) { v = s[t]; add = (t >= off) ? s[t - off] : 0; }
            __syncthreads();
            if (t < 128) s[t] = v + add;
            __syncthreads();
        }
        int boff = (blk > 0) ? s[blk - 1] : 0;
        if (t < 256) {
            int lane = t & 63, w = t >> 6;
            int4 v = ((const int4*)deg4)[blk * 256 + t];
            int tsum = v.x + v.y + v.z + v.w;
            int incl = tsum;
#pragma unroll
            for (int off = 1; off < 64; off <<= 1) {
                int n = __shfl_up(incl, off, 64);
                if (lane >= off) incl += n;
            }
            __shared__ int wsum[4];
            if (lane == 63) wsum[w] = incl;
            __syncthreads();
            int woff = 0;
#pragma unroll
            for (int k = 0; k < 4; k++) woff += (k < w) ? wsum[k] : 0;
            int excl = boff + woff + (incl - tsum);
            int4 r;
            r.x = excl;
            r.y = excl + v.x;
            r.z = excl + v.x + v.y;
            r.w = excl + v.x + v.y + v.z;
            ((int4*)rp4)[blk * 256 + t]  = r;
            ((int4*)cur4)[blk * 256 + t] = r;
            if (blk == 127 && t == 255) rp4[M] = excl + tsum;
        }
    } else {
        s[t] = (t < 400) ? cellcnt[t] : 0;
        __syncthreads();
        for (int off = 1; off < 512; off <<= 1) {
            int v = s[t];
            int add = (t >= off) ? s[t - off] : 0;
            __syncthreads();
            s[t] = v + add;
            __syncthreads();
        }
        if (t < 400) {
            int excl = (t > 0) ? s[t - 1] : 0;
            cellstart[t] = excl;
            cellcur[t]   = excl;
        }
        if (t == 400) cellstart[400] = s[399];
    }
}

// ---------------- K3f: CSR fill + cell fill (fused, vectorized) ------------
__global__ void __launch_bounds__(256) k_fillcell(
    const int* __restrict__ row, const int* __restrict__ col,
    int* __restrict__ cur4, int* __restrict__ cols,
    const float* __restrict__ coords, int* __restrict__ cellcur,
    float4* __restrict__ pts, int EB4, int N) {
    if ((int)blockIdx.x < EB4) {
        int e4 = blockIdx.x * 256 + threadIdx.x;
        int4 r = ((const int4*)row)[e4];
        int4 c = ((const int4*)col)[e4];
        int p0 = atomicAdd(&cur4[r.x * NB + (c.x >> BSH)], 1); cols[p0] = c.x;
        int p1 = atomicAdd(&cur4[r.y * NB + (c.y >> BSH)], 1); cols[p1] = c.y;
        int p2 = atomicAdd(&cur4[r.z * NB + (c.z >> BSH)], 1); cols[p2] = c.z;
        int p3 = atomicAdd(&cur4[r.w * NB + (c.w >> BSH)], 1); cols[p3] = c.w;
    } else {
        int t2 = ((int)blockIdx.x - EB4) * 256 + threadIdx.x;
        float4 cc = ((const float4*)coords)[t2];
        int i0 = t2 * 2;
        int cx0 = (int)(cc.x * 0.02f); if (cx0 > 19) cx0 = 19;
        int cy0 = (int)(cc.y * 0.02f); if (cy0 > 19) cy0 = 19;
        int p0 = atomicAdd(&cellcur[cy0 * 20 + cx0], 1);
        pts[p0] = make_float4(cc.x, cc.y, cc.x * cc.x + cc.y * cc.y,
                              __int_as_float(i0));
        int cx1 = (int)(cc.z * 0.02f); if (cx1 > 19) cx1 = 19;
        int cy1 = (int)(cc.w * 0.02f); if (cy1 > 19) cy1 = 19;
        int p1 = atomicAdd(&cellcur[cy1 * 20 + cx1], 1);
        pts[p1] = make_float4(cc.z, cc.w, cc.z * cc.z + cc.w * cc.w,
                              __int_as_float(i0 + 1));
    }
}

// ---------------- K5: fvar + dgrid fused (256,4), R15-exact gather ---------
// Clamped-dup gather (R16 proved dummy-masking neutral-to-negative: dup
// loads are cache hits, not MSHR occupants). fvar blocks first (co-resident,
// phase-synced bucket sweep, FETCH~80MB); dgrid backfills. FIN additionally
// stores the row degree as float to degf[N] (free coalesced store) so
// k_scal/k_mlp avoid stride-32B rp4 reads. float(int<2^24) exact.
__global__ void __launch_bounds__(256, 4) k_fvar_dgrid(
    const float* __restrict__ x, const int* __restrict__ rp4,
    const int* __restrict__ cols, float* __restrict__ fvar,
    float* __restrict__ degf,
    const float4* __restrict__ pts, const int* __restrict__ cellstart,
    int* __restrict__ dens, int FBk, int N) {
    int wave = threadIdx.x >> 6;
    int lane = threadIdx.x & 63;
    if ((int)blockIdx.x < FBk) {
        int i0 = (blockIdx.x * 4 + wave) * RPW;
        const float4* xb = (const float4*)x;   // 64 float4 per row
        int bnd = rp4[i0 * NB + (lane < 32 ? lane : 32)];

        float4 acc0 = make_float4(0.f, 0.f, 0.f, 0.f);
        float4 acc1 = make_float4(0.f, 0.f, 0.f, 0.f);
        float4 acc2 = make_float4(0.f, 0.f, 0.f, 0.f);
        float4 acc3 = make_float4(0.f, 0.f, 0.f, 0.f);

        for (int b = 0; b < NB; b++) {
#pragma unroll
            for (int r = 0; r < RPW; r++) {
                float4& a = (r == 0) ? acc0 : (r == 1) ? acc1
                          : (r == 2) ? acc2 : acc3;
                int s = __shfl(bnd, r * NB + b, 64);
                int e = __shfl(bnd, r * NB + b + 1, 64);
                for (int p0 = s; p0 < e; p0 += 64) {
                    int m = e - p0; if (m > 64) m = 64;
                    int idx = cols[p0 + (lane < m ? lane : m - 1)];
                    for (int j = 0; j < m; j += 8) {
                        int nb2 = m - j; if (nb2 > 8) nb2 = 8;
                        float4 g0 = xb[(size_t)__shfl(idx, j + 0, 64) * 64 + lane];
                        float4 g1 = xb[(size_t)__shfl(idx, j + 1, 64) * 64 + lane];
                        float4 g2 = xb[(size_t)__shfl(idx, j + 2, 64) * 64 + lane];
                        float4 g3 = xb[(size_t)__shfl(idx, j + 3, 64) * 64 + lane];
                        float4 g4 = xb[(size_t)__shfl(idx, j + 4, 64) * 64 + lane];
                        float4 g5 = xb[(size_t)__shfl(idx, j + 5, 64) * 64 + lane];
                        float4 g6 = xb[(size_t)__shfl(idx, j + 6, 64) * 64 + lane];
                        float4 g7 = xb[(size_t)__shfl(idx, j + 7, 64) * 64 + lane];
                        float w1 = (1 < nb2) ? 1.0f : 0.0f;
                        float w2 = (2 < nb2) ? 1.0f : 0.0f;
                        float w3 = (3 < nb2) ? 1.0f : 0.0f;
                        float w4 = (4 < nb2) ? 1.0f : 0.0f;
                        float w5 = (5 < nb2) ? 1.0f : 0.0f;
                        float w6 = (6 < nb2) ? 1.0f : 0.0f;
                        float w7 = (7 < nb2) ? 1.0f : 0.0f;
                        a.x += g0.x; a.y += g0.y; a.z += g0.z; a.w += g0.w;
                        a.x = fmaf(g1.x, w1, a.x); a.y = fmaf(g1.y, w1, a.y);
                        a.z = fmaf(g1.z, w1, a.z); a.w = fmaf(g1.w, w1, a.w);
                        a.x = fmaf(g2.x, w2, a.x); a.y = fmaf(g2.y, w2, a.y);
                        a.z = fmaf(g2.z, w2, a.z); a.w = fmaf(g2.w, w2, a.w);
                        a.x = fmaf(g3.x, w3, a.x); a.y = fmaf(g3.y, w3, a.y);
                        a.z = fmaf(g3.z, w3, a.z); a.w = fmaf(g3.w, w3, a.w);
                        a.x = fmaf(g4.x, w4, a.x); a.y = fmaf(g4.y, w4, a.y);
                        a.z = fmaf(g4.z, w4, a.z); a.w = fmaf(g4.w, w4, a.w);
                        a.x = fmaf(g5.x, w5, a.x); a.y = fmaf(g5.y, w5, a.y);
                        a.z = fmaf(g5.z, w5, a.z); a.w = fmaf(g5.w, w5, a.w);
                        a.x = fmaf(g6.x, w6, a.x); a.y = fmaf(g6.y, w6, a.y);
                        a.z = fmaf(g6.z, w6, a.z); a.w = fmaf(g6.w, w6, a.w);
                        a.x = fmaf(g7.x, w7, a.x); a.y = fmaf(g7.y, w7, a.y);
                        a.z = fmaf(g7.z, w7, a.z); a.w = fmaf(g7.w, w7, a.w);
                    }
                }
            }
        }

#define FIN(RR, ACCR)                                                   \
        {                                                               \
            int i = i0 + (RR);                                          \
            int d_ = __shfl(bnd, (RR) * NB + NB, 64) -                  \
                     __shfl(bnd, (RR) * NB, 64);                        \
            float cnt = fmaxf((float)d_, 1.0f);                         \
            float4 xi = xb[(size_t)i * 64 + lane];                      \
            float dx = xi.x - ACCR.x / cnt;                             \
            float dy = xi.y - ACCR.y / cnt;                             \
            float dz = xi.z - ACCR.z / cnt;                             \
            float dw = xi.w - ACCR.w / cnt;                             \
            float ss = dx * dx + dy * dy + dz * dz + dw * dw;           \
            _Pragma("unroll")                                           \
            for (int off = 32; off > 0; off >>= 1) ss += __shfl_xor(ss, off, 64); \
            if (lane == 0) { fvar[i] = sqrtf(ss); degf[i] = (float)d_; } \
        }

        FIN(0, acc0);
        FIN(1, acc1);
        FIN(2, acc2);
        FIN(3, acc3);
#undef FIN
    } else {
        // dgrid: one wave per point (R6-proven body)
        int t = ((int)blockIdx.x - FBk) * 4 + wave;
        float4 p = pts[t];
        int cx = (int)(p.x * 0.02f); if (cx > 19) cx = 19;
        int cy = (int)(p.y * 0.02f); if (cy > 19) cy = 19;
        int x0 = cx - 2; if (x0 < 0) x0 = 0;
        int x1 = cx + 2; if (x1 > 19) x1 = 19;
        int y0 = cy - 2; if (y0 < 0) y0 = 0;
        int y1 = cy + 2; if (y1 > 19) y1 = 19;
        int cnt = 0;
        for (int yy = y0; yy <= y1; yy++) {
            int rowb = yy * 20;
            int s = cellstart[rowb + x0];
            int e = cellstart[rowb + x1 + 1];
            for (int q = s + lane; q < e; q += 64) {
                float4 pq = pts[q];
                float dot = p.x * pq.x + p.y * pq.y;
                float d2 = (p.z + pq.z) - 2.0f * dot;
                cnt += (d2 <= R2) ? 1 : 0;
            }
        }
#pragma unroll
        for (int off = 32; off > 0; off >>= 1) cnt += __shfl_xor(cnt, off, 64);
        if (lane == 0) dens[__float_as_int(p.w)] = cnt;
    }
}

// ---------------- K5b: maxima reduction (compact degf, coalesced) ----------
__global__ void __launch_bounds__(256) k_scal(
    const float* __restrict__ degf, const int* __restrict__ dens,
    const float* __restrict__ fvar, int* __restrict__ scal, int N) {
    __shared__ float sd[4];
    __shared__ int sn[4];
    __shared__ float sf[4];
    int t = threadIdx.x;
    int g = blockIdx.x * 256 + t;
    int stride = 256 * gridDim.x;
    float md = 0.f;
    int mn = 0;
    float mf = 0.f;
    for (int i = g; i < N; i += stride) {
        md = fmaxf(md, degf[i]);
        mn = max(mn, dens[i]);
        mf = fmaxf(mf, fvar[i]);
    }
#pragma unroll
    for (int off = 32; off > 0; off >>= 1) {
        md = fmaxf(md, __shfl_xor(md, off, 64));
        mn = max(mn, __shfl_xor(mn, off, 64));
        mf = fmaxf(mf, __shfl_xor(mf, off, 64));
    }
    int w = t >> 6, l = t & 63;
    if (l == 0) { sd[w] = md; sn[w] = mn; sf[w] = mf; }
    __syncthreads();
    if (t == 0) {
#pragma unroll
        for (int k = 1; k < 4; k++) {
            md = fmaxf(md, sd[k]);
            mn = max(mn, sn[k]);
            mf = fmaxf(mf, sf[k]);
        }
        atomicMax(&scal[0], __float_as_int(md));   // nonneg float: int-max ok
        atomicMax(&scal[1], mn);
        atomicMax(&scal[2], __float_as_int(mf));
    }
}

// ---------------- K6: tiny MLP (compact degf) ----------------
__global__ void __launch_bounds__(256) k_mlp(
    const float* __restrict__ w1, const float* __restrict__ b1,
    const float* __restrict__ w2, const float* __restrict__ b2,
    const float* __restrict__ degf, const int* __restrict__ dens,
    const float* __restrict__ fvar, const int* __restrict__ scal,
    float* __restrict__ out, int N) {
    __shared__ float sh_h[HH];
    int j = threadIdx.x;
    float wv[HH];
#pragma unroll
    for (int l = 0; l < HH; l++) wv[l] = w2[l * H + j];
    float bj = b2[j];
    float maxdeg  = __int_as_float(scal[0]) + EPSF;
    float maxdens = (float)(scal[1] - 1) + EPSF;
    float maxfv   = __int_as_float(scal[2]) + EPSF;
    float w1a = 0.f, w1b = 0.f, w1c = 0.f, b1j = 0.f;
    if (j < HH) { w1a = w1[j]; w1b = w1[HH + j]; w1c = w1[2 * HH + j]; b1j = b1[j]; }
    for (int i = blockIdx.x; i < N; i += gridDim.x) {
        float f0 = degf[i] / maxdeg;
        float f1 = (float)(dens[i] - 1) / maxdens;
        float f2 = fvar[i] / maxfv;
        if (j < HH) {
            float h = f0 * w1a + f1 * w1b + f2 * w1c + b1j;
            sh_h[j] = fmaxf(h, 0.0f);
        }
        __syncthreads();
        float acc = bj;
#pragma unroll
        for (int l = 0; l < HH; l++) acc = fmaf(sh_h[l], wv[l], acc);
        out[(size_t)i * H + j] = acc;
        __syncthreads();
    }
}

extern "C" void kernel_launch(void* const* d_in, const int* in_sizes, int n_in,
                              void* d_out, int out_size, void* d_ws, size_t ws_size,
                              hipStream_t stream) {
    const float* x      = (const float*)d_in[0];
    const int*   ei     = (const int*)d_in[1];
    const float* coords = (const float*)d_in[2];
    const float* w1     = (const float*)d_in[3];
    const float* b1     = (const float*)d_in[4];
    const float* w2     = (const float*)d_in[5];
    const float* b2     = (const float*)d_in[6];
    float* out = (float*)d_out;

    const int N = in_sizes[2] / 2;   // 16384
    const int E = in_sizes[1] / 2;   // 524288
    const int M = N * NB;            // 131072
    const int NBLK = M / 1024;       // 128 scan blocks
    const int EB4 = E / 1024;        // 512 edge blocks (4 edges/thread)
    const int CB2 = N / 512;         // 32 coord blocks (2 points/thread)
    const int FBk = N / (4 * RPW);   // 1024 fvar blocks
    const int DB  = N / 4;           // 4096 dgrid blocks
    const int* row = ei;
    const int* col = ei + E;

    // workspace layout (int32 elements; int4/float4 arrays 16B-aligned)
    int* ws        = (int*)d_ws;
    int* scal      = ws;                       // [4]     zeroed
    int* deg4      = ws + 4;                   // [M]     zeroed  (16B-aligned)
    int* cellcnt   = ws + 4 + M;               // [404]   zeroed  (400 used)
    int* rp4       = ws + 408 + M;             // [M+4]           (16B-aligned)
    int* cur4      = rp4 + M + 4;              // [M]             (16B-aligned)
    int* cellstart = cur4 + M;                 // [404]   (401 used)
    int* cellcur   = cellstart + 404;          // [400]
    int* dens_cnt  = cellcur + 400;            // [N]
    float* fvarp   = (float*)(dens_cnt + N);   // [N]
    int* bsum      = dens_cnt + 2 * N;         // [128]
    int* boff      = bsum + 128;               // [128] (layout pad)
    int* cols      = boff + 128;               // [E]
    float4* pts    = (float4*)(cols + E);      // [N]  (16B-aligned)
    float* degf    = (float*)(pts + N);        // [N]

    hipMemsetAsync(ws, 0, (size_t)(408 + M) * sizeof(int), stream);

    k_degcell<<<EB4 + CB2, 256, 0, stream>>>(row, col, deg4, coords, cellcnt,
                                             EB4, N);
    k_bsum<<<NBLK, 256, 0, stream>>>(deg4, bsum);
    k_scatcell<<<NBLK + 1, 512, 0, stream>>>(deg4, bsum, rp4, cur4, M,
                                             cellcnt, cellstart, cellcur);
    k_fillcell<<<EB4 + CB2, 256, 0, stream>>>(row, col, cur4, cols,
                                              coords, cellcur, pts, EB4, N);

    k_fvar_dgrid<<<FBk + DB, 256, 0, stream>>>(x, rp4, cols, fvarp, degf,
                                               pts, cellstart, dens_cnt, FBk, N);

    k_scal<<<64, 256, 0, stream>>>(degf, dens_cnt, fvarp, scal, N);

    k_mlp<<<1024, 256, 0, stream>>>(w1, b1, w2, b2, degf, dens_cnt, fvarp, scal,
                                    out, N);
}